// Round 11
// baseline (80.642 us; speedup 1.0000x reference)
//
#include <hip/hip_runtime.h>

#define NG 3
#define HW 4096
#define NB 256
#define NSPOT 32
#define TPB 1024
#define PXT 4               // pixels per thread (1024*4 = 4096), two halves of 2
#define NWAVE (TPB / 64)    // 16

// -log2(e)/2
#define NHALF_LOG2E -0.7213475204444817f
#define LN2 0.6931471805599453f

typedef float f32x2 __attribute__((ext_vector_type(2)));

__device__ __forceinline__ void coeffs_half(const f32x2 p_in, const f32x2 mu_in[NG],
                                            const f32x2 sg_in[NG],
                                            f32x2 A[NG], f32x2 C[1], float& psum) {
    // a_g = -log2e/(2 sigma_g^2);  C' = log2 p - log2(prod sigma)
    float c0, c1;
    {
        float p = fmaxf(p_in.x, 1e-20f);
        psum += p;
        c0 = __builtin_amdgcn_logf(p);
        float p2 = fmaxf(p_in.y, 1e-20f);
        psum += p2;
        c1 = __builtin_amdgcn_logf(p2);
    }
    float prod0 = 1.f, prod1 = 1.f;
#pragma unroll
    for (int g = 0; g < NG; ++g) {
        float s0 = fmaxf(sg_in[g].x, 1e-10f);
        float s1 = fmaxf(sg_in[g].y, 1e-10f);
        prod0 *= s0;
        prod1 *= s1;
        A[g] = (f32x2){NHALF_LOG2E * __builtin_amdgcn_rcpf(s0 * s0),
                       NHALF_LOG2E * __builtin_amdgcn_rcpf(s1 * s1)};
    }
    C[0] = (f32x2){c0 - __builtin_amdgcn_logf(prod0),
                   c1 - __builtin_amdgcn_logf(prod1)};
}

__global__ __launch_bounds__(TPB) void gmm_fused(const float* __restrict__ feat,
                                                 const float* __restrict__ tgt,
                                                 float* __restrict__ out) {
    const int b = blockIdx.x;
    const int tid = threadIdx.x;
    const int lane = tid & 63;
    const int wv = tid >> 6;

    __shared__ float Ssh[NWAVE][NSPOT];
    __shared__ float Psh[NWAVE];

    // block-uniform spot table base -> scalar (SGPR) loads
    const float* __restrict__ tb = tgt + (size_t)b * (NSPOT * 4);

    const float* fb = feat + (size_t)b * (7 * HW);
    const int p4 = tid * 4;

    // ---- issue ALL loads up front as float2 halves (A: px 0-1, B: px 2-3) ----
    f32x2 la[7], lb[7];
#pragma unroll
    for (int pl = 0; pl < 7; ++pl)
        la[pl] = *(const f32x2*)(fb + pl * HW + p4);
#pragma unroll
    for (int pl = 0; pl < 7; ++pl)
        lb[pl] = *(const f32x2*)(fb + pl * HW + p4 + 2);

    float psum = 0.f;

    // ---- half A: coefficients (needs only la[0..6]) ----
    f32x2 MUa[NG] = {la[1], la[2], la[3]};
    f32x2 Aa[NG], Ca[1];
    coeffs_half(la[0], MUa, &la[4], Aa, Ca, psum);

    // ---- half A spot loop (hides half-B load latency) ----
    float acc[NSPOT];
#pragma unroll
    for (int s = 0; s < NSPOT; ++s) {
        const float tx = tb[4 * s + 1];   // uniform -> SGPR
        const float ty = tb[4 * s + 2];
        const float tz = tb[4 * s + 3];
        f32x2 x2 = Ca[0];
        {
            f32x2 z = tx - MUa[0];
            x2 += (z * Aa[0]) * z;
        }
        {
            f32x2 z = ty - MUa[1];
            x2 += (z * Aa[1]) * z;
        }
        {
            f32x2 z = tz - MUa[2];
            x2 += (z * Aa[2]) * z;
        }
        acc[s] = __builtin_amdgcn_exp2f(x2.x) + __builtin_amdgcn_exp2f(x2.y);
    }

    // ---- half B: coefficients ----
    f32x2 MUb[NG] = {lb[1], lb[2], lb[3]};
    f32x2 Ab[NG], Cb[1];
    coeffs_half(lb[0], MUb, &lb[4], Ab, Cb, psum);

    // ---- half B spot loop ----
#pragma unroll
    for (int s = 0; s < NSPOT; ++s) {
        const float tx = tb[4 * s + 1];
        const float ty = tb[4 * s + 2];
        const float tz = tb[4 * s + 3];
        f32x2 x2 = Cb[0];
        {
            f32x2 z = tx - MUb[0];
            x2 += (z * Ab[0]) * z;
        }
        {
            f32x2 z = ty - MUb[1];
            x2 += (z * Ab[1]) * z;
        }
        {
            f32x2 z = tz - MUb[2];
            x2 += (z * Ab[2]) * z;
        }
        acc[s] += __builtin_amdgcn_exp2f(x2.x) + __builtin_amdgcn_exp2f(x2.y);
    }

    // ---- multi-value wave reduction: 32 values across 64 lanes ----
#define RSTEP(D, HALF)                                          \
    {                                                           \
        const bool hi = (lane & (D)) != 0;                      \
        _Pragma("unroll") for (int i = 0; i < (HALF); ++i) {    \
            float send = hi ? acc[i] : acc[i + (HALF)];         \
            float recv = __shfl_xor(send, (D), 64);             \
            acc[i] = (hi ? acc[i + (HALF)] : acc[i]) + recv;    \
        }                                                       \
    }
    RSTEP(32, 16)
    RSTEP(16, 8)
    RSTEP(8, 4)
    RSTEP(4, 2)
    RSTEP(2, 1)
#undef RSTEP
    acc[0] += __shfl_xor(acc[0], 1, 64);
    if ((lane & 1) == 0) Ssh[wv][lane >> 1] = acc[0];

    float ps = psum;
#pragma unroll
    for (int m = 1; m < 64; m <<= 1) ps += __shfl_xor(ps, m, 64);
    if (lane == 0) Psh[wv] = ps;
    __syncthreads();

    // ---- final block reduction on wave 0 ----
    if (tid < 64) {
        float contrib = 0.f, msum = 0.f;
        if (tid < NSPOT) {
            float S = 0.f;
#pragma unroll
            for (int w = 0; w < NWAVE; ++w) S += Ssh[w][tid];
            float mask = tgt[(size_t)b * (NSPOT * 4) + tid * 4];
            contrib = mask * __builtin_amdgcn_logf(S);  // mask * log2(S)
            msum = mask;
        }
        float pv = (tid < NWAVE) ? Psh[tid] : 0.f;
#pragma unroll
        for (int m = 1; m < 64; m <<= 1) {
            contrib += __shfl_xor(contrib, m, 64);
            msum += __shfl_xor(msum, m, 64);
            pv += __shfl_xor(pv, m, 64);
        }
        if (tid == 0)
            out[b] = -LN2 * (contrib - msum * __builtin_amdgcn_logf(pv));
    }
}

extern "C" void kernel_launch(void* const* d_in, const int* in_sizes, int n_in,
                              void* d_out, int out_size, void* d_ws, size_t ws_size,
                              hipStream_t stream) {
    const float* feat = (const float*)d_in[0];
    const float* tgt = (const float*)d_in[1];
    float* out = (float*)d_out;

    gmm_fused<<<NB, TPB, 0, stream>>>(feat, tgt, out);
}

// Round 12
// 79.051 us; speedup vs baseline: 1.0201x; 1.0201x over previous
//
#include <hip/hip_runtime.h>

#define NG 3
#define HW 4096
#define NB 256
#define NSPOT 32
#define TPB 1024
#define PXT 4               // pixels per thread (1024*4 = 4096)
#define NWAVE (TPB / 64)    // 16

// -log2(e)/2
#define NHALF_LOG2E -0.7213475204444817f
#define LN2 0.6931471805599453f

typedef float f32x2 __attribute__((ext_vector_type(2)));

__global__ __launch_bounds__(TPB) void gmm_fused(const float* __restrict__ feat,
                                                 const float* __restrict__ tgt,
                                                 float* __restrict__ out) {
    const int b = blockIdx.x;
    const int tid = threadIdx.x;
    const int lane = tid & 63;
    const int wv = tid >> 6;

    __shared__ float Ssh[NWAVE][NSPOT];
    __shared__ float Psh[NWAVE];

    // block-uniform spot table base -> scalar (SGPR) loads, no LDS staging
    const float* __restrict__ tb = tgt + (size_t)b * (NSPOT * 4);

    // ---- load 4 contiguous pixels x 7 planes (float4, coalesced) ----
    const float* fb = feat + (size_t)b * (7 * HW);
    const int p4 = tid * 4;

    float4 f0 = *(const float4*)(fb + 0 * HW + p4);
    float4 f1 = *(const float4*)(fb + 1 * HW + p4);
    float4 f2 = *(const float4*)(fb + 2 * HW + p4);
    float4 f3 = *(const float4*)(fb + 3 * HW + p4);
    float4 f4v = *(const float4*)(fb + 4 * HW + p4);
    float4 f5 = *(const float4*)(fb + 5 * HW + p4);
    float4 f6 = *(const float4*)(fb + 6 * HW + p4);

    float pr[PXT] = {f0.x, f0.y, f0.z, f0.w};
    float mu_s[NG][PXT] = {{f1.x, f1.y, f1.z, f1.w},
                           {f2.x, f2.y, f2.z, f2.w},
                           {f3.x, f3.y, f3.z, f3.w}};
    float sg_s[NG][PXT] = {{f4v.x, f4v.y, f4v.z, f4v.w},
                           {f5.x, f5.y, f5.z, f5.w},
                           {f6.x, f6.y, f6.z, f6.w}};

    // ---- per-pixel derived coefficients (numerically stable form) ----
    // a_g = -log2e/(2 sigma_g^2)
    // C'  = log2 p - log2(sigma0*sigma1*sigma2)   (product in [1e-30, ~1])
    // x(t) = C' + sum_g (z_g * a_g) * z_g,  z_g = t_g - mu_g  (spot terms <= 0)
    float a_s[NG][PXT], c_s[PXT];
    float psum = 0.f;
#pragma unroll
    for (int k = 0; k < PXT; ++k) {
        float p = fmaxf(pr[k], 1e-20f);
        psum += p;
        float prod = 1.f;
#pragma unroll
        for (int g = 0; g < NG; ++g) {
            float s = fmaxf(sg_s[g][k], 1e-10f);
            prod *= s;
            a_s[g][k] = NHALF_LOG2E * __builtin_amdgcn_rcpf(s * s);
        }
        c_s[k] = __builtin_amdgcn_logf(p) - __builtin_amdgcn_logf(prod);
    }

    // pack into float2 pairs for packed f32 math
    f32x2 MU[NG][2], A[NG][2], C[2];
#pragma unroll
    for (int pp = 0; pp < 2; ++pp) {
        C[pp] = (f32x2){c_s[2 * pp], c_s[2 * pp + 1]};
#pragma unroll
        for (int g = 0; g < NG; ++g) {
            MU[g][pp] = (f32x2){mu_s[g][2 * pp], mu_s[g][2 * pp + 1]};
            A[g][pp] = (f32x2){a_s[g][2 * pp], a_s[g][2 * pp + 1]};
        }
    }

    // ---- main loop: 32 spots x 2 pixel-pairs; stable quadratic + exp2 ----
    float acc[NSPOT];
#pragma unroll
    for (int s = 0; s < NSPOT; ++s) {
        const float tx = tb[4 * s + 1];   // uniform -> SGPR
        const float ty = tb[4 * s + 2];
        const float tz = tb[4 * s + 3];
        f32x2 x[2];
#pragma unroll
        for (int pp = 0; pp < 2; ++pp) {
            f32x2 x2 = C[pp];
            {
                f32x2 z = tx - MU[0][pp];
                x2 += (z * A[0][pp]) * z;
            }
            {
                f32x2 z = ty - MU[1][pp];
                x2 += (z * A[1][pp]) * z;
            }
            {
                f32x2 z = tz - MU[2][pp];
                x2 += (z * A[2][pp]) * z;
            }
            x[pp] = x2;
        }
        float e0 = __builtin_amdgcn_exp2f(x[0].x) + __builtin_amdgcn_exp2f(x[0].y);
        float e1 = __builtin_amdgcn_exp2f(x[1].x) + __builtin_amdgcn_exp2f(x[1].y);
        acc[s] = e0 + e1;
    }

    // ---- multi-value wave reduction: 32 values across 64 lanes ----
#define RSTEP(D, HALF)                                          \
    {                                                           \
        const bool hi = (lane & (D)) != 0;                      \
        _Pragma("unroll") for (int i = 0; i < (HALF); ++i) {    \
            float send = hi ? acc[i] : acc[i + (HALF)];         \
            float recv = __shfl_xor(send, (D), 64);             \
            acc[i] = (hi ? acc[i + (HALF)] : acc[i]) + recv;    \
        }                                                       \
    }
    RSTEP(32, 16)
    RSTEP(16, 8)
    RSTEP(8, 4)
    RSTEP(4, 2)
    RSTEP(2, 1)
#undef RSTEP
    acc[0] += __shfl_xor(acc[0], 1, 64);
    if ((lane & 1) == 0) Ssh[wv][lane >> 1] = acc[0];

    float ps = psum;
#pragma unroll
    for (int m = 1; m < 64; m <<= 1) ps += __shfl_xor(ps, m, 64);
    if (lane == 0) Psh[wv] = ps;
    __syncthreads();

    // ---- final block reduction on wave 0 ----
    if (tid < 64) {
        float contrib = 0.f, msum = 0.f;
        if (tid < NSPOT) {
            float S = 0.f;
#pragma unroll
            for (int w = 0; w < NWAVE; ++w) S += Ssh[w][tid];
            float mask = tgt[(size_t)b * (NSPOT * 4) + tid * 4];
            contrib = mask * __builtin_amdgcn_logf(S);  // mask * log2(S)
            msum = mask;
        }
        float pv = (tid < NWAVE) ? Psh[tid] : 0.f;
#pragma unroll
        for (int m = 1; m < 64; m <<= 1) {
            contrib += __shfl_xor(contrib, m, 64);
            msum += __shfl_xor(msum, m, 64);
            pv += __shfl_xor(pv, m, 64);
        }
        if (tid == 0)
            out[b] = -LN2 * (contrib - msum * __builtin_amdgcn_logf(pv));
    }
}

extern "C" void kernel_launch(void* const* d_in, const int* in_sizes, int n_in,
                              void* d_out, int out_size, void* d_ws, size_t ws_size,
                              hipStream_t stream) {
    const float* feat = (const float*)d_in[0];
    const float* tgt = (const float*)d_in[1];
    float* out = (float*)d_out;

    gmm_fused<<<NB, TPB, 0, stream>>>(feat, tgt, out);
}